// Round 1
// baseline (531.294 us; speedup 1.0000x reference)
//
#include <hip/hip_runtime.h>

#define HD 64   // hidden dim D

// ---- degree: one thread per edge ----
__global__ void deg_kernel(const int* __restrict__ dst, float* __restrict__ deg, int E) {
    int e = blockIdx.x * blockDim.x + threadIdx.x;
    if (e < E) atomicAdd(&deg[dst[e]], 1.0f);
}

// ---- scatter-add: one wave (64 lanes) per edge, lane = feature dim ----
__global__ void scatter_kernel(const float* __restrict__ h, const int* __restrict__ src,
                               const int* __restrict__ dst, float* __restrict__ neigh,
                               int E) {
    long long tid = (long long)blockIdx.x * blockDim.x + threadIdx.x;
    int e = (int)(tid >> 6);
    int d = (int)(tid & 63);
    if (e >= E) return;
    int s = src[e];
    int t = dst[e];
    float v = h[(long long)s * HD + d];
    atomicAdd(&neigh[(long long)t * HD + d], v);
}

// ---- per-node: z = [h | neigh/deg]; out = l2norm(relu(z @ W^T)) ----
// One wave per node; lane = output dim. W[k] (64x128) lives in 128 VGPRs/lane.
__global__ void node_kernel(const float* __restrict__ h_in,
                            const float* __restrict__ neigh,
                            const float* __restrict__ deg,
                            const float* __restrict__ Wk,
                            float* __restrict__ h_out, int N) {
    __shared__ float zl[4][128];           // per-wave z staging
    const int lane = threadIdx.x & 63;
    const int w = threadIdx.x >> 6;

    // W row for this lane (output dim) -> registers. 32KB per wave, L2-cached.
    float wreg[128];
#pragma unroll
    for (int j4 = 0; j4 < 32; ++j4) {
        float4 t = *(const float4*)&Wk[lane * 128 + j4 * 4];
        wreg[j4 * 4 + 0] = t.x;
        wreg[j4 * 4 + 1] = t.y;
        wreg[j4 * 4 + 2] = t.z;
        wreg[j4 * 4 + 3] = t.w;
    }

    const int nwaves = gridDim.x * 4;
    for (int node = blockIdx.x * 4 + w; node < N; node += nwaves) {
        float dg = deg[node];                       // wave-uniform broadcast load
        float inv = dg > 0.f ? 1.f / dg : 0.f;
        float hv = h_in[node * HD + lane];
        float nv = neigh[node * HD + lane] * inv;

        __builtin_amdgcn_wave_barrier();
        zl[w][lane] = hv;
        zl[w][64 + lane] = nv;
        asm volatile("s_waitcnt lgkmcnt(0)" ::: "memory");
        __builtin_amdgcn_wave_barrier();

        float acc = 0.f;
#pragma unroll
        for (int j4 = 0; j4 < 32; ++j4) {
            float4 z4 = *(const float4*)&zl[w][j4 * 4];   // broadcast read, conflict-free
            acc = fmaf(z4.x, wreg[j4 * 4 + 0], acc);
            acc = fmaf(z4.y, wreg[j4 * 4 + 1], acc);
            acc = fmaf(z4.z, wreg[j4 * 4 + 2], acc);
            acc = fmaf(z4.w, wreg[j4 * 4 + 3], acc);
        }
        __builtin_amdgcn_wave_barrier();   // keep reads ordered before next iter's writes

        float v = fmaxf(acc, 0.f);
        // L2 norm across the 64 lanes (output dims)
        float s = v * v;
#pragma unroll
        for (int off = 32; off >= 1; off >>= 1) s += __shfl_xor(s, off, 64);
        float nrm = sqrtf(s);
        float scale = 1.f / fmaxf(nrm, 1e-12f);
        h_out[node * HD + lane] = v * scale;
    }
}

extern "C" void kernel_launch(void* const* d_in, const int* in_sizes, int n_in,
                              void* d_out, int out_size, void* d_ws, size_t ws_size,
                              hipStream_t stream) {
    const float* x    = (const float*)d_in[0];
    const float* W    = (const float*)d_in[1];
    const int*   esrc = (const int*)d_in[2];
    const int*   edst = (const int*)d_in[3];
    float* out = (float*)d_out;

    const int N = in_sizes[0] / HD;
    const int E = in_sizes[2];
    const int DEPTH = in_sizes[1] / (HD * 2 * HD);

    // workspace layout: deg[N] | neigh[N*HD]
    char* ws = (char*)d_ws;
    float* deg = (float*)ws;
    size_t degBytes = (((size_t)N * sizeof(float)) + 255) & ~(size_t)255;
    float* neigh = (float*)(ws + degBytes);

    hipMemsetAsync(deg, 0, (size_t)N * sizeof(float), stream);
    deg_kernel<<<(E + 255) / 256, 256, 0, stream>>>(edst, deg, E);

    const float* h_in = x;
    for (int k = 0; k < DEPTH; ++k) {
        hipMemsetAsync(neigh, 0, (size_t)N * HD * sizeof(float), stream);
        long long scatter_threads = (long long)E * 64;
        int scatter_blocks = (int)((scatter_threads + 255) / 256);
        scatter_kernel<<<scatter_blocks, 256, 0, stream>>>(h_in, esrc, edst, neigh, E);
        node_kernel<<<1024, 256, 0, stream>>>(h_in, neigh, deg,
                                              W + (size_t)k * HD * 2 * HD, out, N);
        h_in = out;
    }
}

// Round 2
// 343.704 us; speedup vs baseline: 1.5458x; 1.5458x over previous
//
#include <hip/hip_runtime.h>

#define HD 64   // hidden dim D

// ---- degree histogram (int) ----
__global__ void deg_kernel(const int* __restrict__ dst, int* __restrict__ deg, int E) {
    int e = blockIdx.x * blockDim.x + threadIdx.x;
    if (e < E) atomicAdd(&deg[dst[e]], 1);
}

// ---- single-block exclusive scan over deg[N] -> row_start, cursor, inv_deg ----
__global__ void scan_kernel(const int* __restrict__ deg, int* __restrict__ row_start,
                            int* __restrict__ cursor, float* __restrict__ inv_deg, int N) {
    const int tid = threadIdx.x;              // 1024 threads = 16 waves
    const int lane = tid & 63, wid = tid >> 6;
    __shared__ int wtot[16], woff[16];
    __shared__ int base, ctot;
    if (tid == 0) base = 0;
    __syncthreads();
    for (int c = 0; c < N; c += 1024) {
        int i = c + tid;
        int v = (i < N) ? deg[i] : 0;
        int s = v;
#pragma unroll
        for (int off = 1; off < 64; off <<= 1) {
            int t = __shfl_up(s, off, 64);
            if (lane >= off) s += t;
        }
        if (lane == 63) wtot[wid] = s;
        __syncthreads();
        if (tid == 0) {
            int r = 0;
            for (int k = 0; k < 16; ++k) { woff[k] = r; r += wtot[k]; }
            ctot = r;
        }
        __syncthreads();
        if (i < N) {
            int excl = base + woff[wid] + (s - v);
            row_start[i] = excl;
            cursor[i]    = excl;
            inv_deg[i]   = (v > 0) ? 1.0f / (float)v : 0.0f;
        }
        __syncthreads();
        if (tid == 0) base += ctot;
        __syncthreads();
    }
    if (tid == 0) row_start[N] = base;
}

// ---- scatter edges into CSR slots ----
__global__ void fill_kernel(const int* __restrict__ src, const int* __restrict__ dst,
                            int* __restrict__ cursor, int* __restrict__ csr, int E) {
    int e = blockIdx.x * blockDim.x + threadIdx.x;
    if (e < E) {
        int p = atomicAdd(&cursor[dst[e]], 1);
        csr[p] = src[e];
    }
}

// ---- fused per-layer: gather-mean + [h|neigh] @ W^T + relu + L2-norm ----
// One wave per node; lane = output dim. W (64x128) in 128 VGPRs/lane.
__global__ __launch_bounds__(256) void layer_kernel(
    const float* __restrict__ h_in, const float* __restrict__ inv_deg,
    const int* __restrict__ row_start, const int* __restrict__ csr,
    const float* __restrict__ Wk, float* __restrict__ h_out, int N) {
    __shared__ float zl[4][128];
    const int lane = threadIdx.x & 63;
    const int w = threadIdx.x >> 6;

    float wreg[128];
#pragma unroll
    for (int j4 = 0; j4 < 32; ++j4) {
        float4 t = *(const float4*)&Wk[lane * 128 + j4 * 4];
        wreg[j4 * 4 + 0] = t.x;
        wreg[j4 * 4 + 1] = t.y;
        wreg[j4 * 4 + 2] = t.z;
        wreg[j4 * 4 + 3] = t.w;
    }

    const int nwaves = gridDim.x * 4;
    for (int node = blockIdx.x * 4 + w; node < N; node += nwaves) {
        const int nu = __builtin_amdgcn_readfirstlane(node);
        const int rs = row_start[nu];
        const int re = row_start[nu + 1];

        // gather-accumulate neighbor rows (coalesced 256B row loads, 4-deep ILP)
        float a0 = 0.f, a1 = 0.f, a2 = 0.f, a3 = 0.f;
        int j = rs;
        for (; j + 4 <= re; j += 4) {
            int s0 = __builtin_amdgcn_readfirstlane(csr[j]);
            int s1 = __builtin_amdgcn_readfirstlane(csr[j + 1]);
            int s2 = __builtin_amdgcn_readfirstlane(csr[j + 2]);
            int s3 = __builtin_amdgcn_readfirstlane(csr[j + 3]);
            a0 += h_in[(long long)s0 * HD + lane];
            a1 += h_in[(long long)s1 * HD + lane];
            a2 += h_in[(long long)s2 * HD + lane];
            a3 += h_in[(long long)s3 * HD + lane];
        }
        for (; j < re; ++j) {
            int s0 = __builtin_amdgcn_readfirstlane(csr[j]);
            a0 += h_in[(long long)s0 * HD + lane];
        }
        float nv = ((a0 + a1) + (a2 + a3)) * inv_deg[nu];
        float hv = h_in[(long long)nu * HD + lane];

        __builtin_amdgcn_wave_barrier();
        zl[w][lane] = hv;
        zl[w][64 + lane] = nv;
        asm volatile("s_waitcnt lgkmcnt(0)" ::: "memory");
        __builtin_amdgcn_wave_barrier();

        float acc = 0.f;
#pragma unroll
        for (int j4 = 0; j4 < 32; ++j4) {
            float4 z4 = *(const float4*)&zl[w][j4 * 4];   // broadcast, conflict-free
            acc = fmaf(z4.x, wreg[j4 * 4 + 0], acc);
            acc = fmaf(z4.y, wreg[j4 * 4 + 1], acc);
            acc = fmaf(z4.z, wreg[j4 * 4 + 2], acc);
            acc = fmaf(z4.w, wreg[j4 * 4 + 3], acc);
        }
        __builtin_amdgcn_wave_barrier();

        float v = fmaxf(acc, 0.f);
        float sq = v * v;
#pragma unroll
        for (int off = 32; off >= 1; off >>= 1) sq += __shfl_xor(sq, off, 64);
        float scale = 1.f / fmaxf(sqrtf(sq), 1e-12f);
        h_out[(long long)nu * HD + lane] = v * scale;
    }
}

extern "C" void kernel_launch(void* const* d_in, const int* in_sizes, int n_in,
                              void* d_out, int out_size, void* d_ws, size_t ws_size,
                              hipStream_t stream) {
    const float* x    = (const float*)d_in[0];
    const float* W    = (const float*)d_in[1];
    const int*   esrc = (const int*)d_in[2];
    const int*   edst = (const int*)d_in[3];
    float* out = (float*)d_out;

    const int N = in_sizes[0] / HD;
    const int E = in_sizes[2];
    const int DEPTH = in_sizes[1] / (HD * 2 * HD);

    // workspace layout: deg[N] | row_start[N+1] | cursor[N] | inv_deg[N] | csr[E] | h1[N*HD]
    auto align256 = [](size_t v) { return (v + 255) & ~(size_t)255; };
    char* ws = (char*)d_ws;
    int*   deg       = (int*)ws;                 ws += align256((size_t)N * 4);
    int*   row_start = (int*)ws;                 ws += align256((size_t)(N + 1) * 4);
    int*   cursor    = (int*)ws;                 ws += align256((size_t)N * 4);
    float* inv_deg   = (float*)ws;               ws += align256((size_t)N * 4);
    int*   csr       = (int*)ws;                 ws += align256((size_t)E * 4);
    float* h1        = (float*)ws;

    hipMemsetAsync(deg, 0, (size_t)N * sizeof(int), stream);
    deg_kernel<<<(E + 255) / 256, 256, 0, stream>>>(edst, deg, E);
    scan_kernel<<<1, 1024, 0, stream>>>(deg, row_start, cursor, inv_deg, N);
    fill_kernel<<<(E + 255) / 256, 256, 0, stream>>>(esrc, edst, cursor, csr, E);

    const float* h_in = x;
    for (int k = 0; k < DEPTH; ++k) {
        // ping-pong so a layer never reads and writes the same buffer
        float* dst = (((DEPTH - 1 - k) & 1) == 0) ? out : h1;
        layer_kernel<<<1024, 256, 0, stream>>>(h_in, inv_deg, row_start, csr,
                                               W + (size_t)k * HD * 2 * HD, dst, N);
        h_in = dst;
    }
}